// Round 14
// baseline (256.355 us; speedup 1.0000x reference)
//
#include <hip/hip_runtime.h>
#include <hip/hip_fp16.h>
#include <stdint.h>

typedef __attribute__((ext_vector_type(4))) int int32x4;
typedef __attribute__((ext_vector_type(4))) float float32x4;

#define TOKENS 8192
#define IN_F   4096
#define OUT_F  4096
#define BM 256
#define BN 256
#define BK 128              // int8 per K-tile = 128 B rows
#define NT (IN_F / BK)      // 32 K-tiles
#define ESTR 260            // epilogue LDS row stride (f32): 2-way bank alias = free

#define AS1 __attribute__((address_space(1)))
#define AS3 __attribute__((address_space(3)))

// ------- fused pack: int32->int8 for x and w, plus bias tuple-output -------
__global__ __launch_bounds__(256)
void pack_all_kernel(const int* __restrict__ x32, const int* __restrict__ w32,
                     const float* __restrict__ bias,
                     uint32_t* __restrict__ x8, uint32_t* __restrict__ w8,
                     float* __restrict__ bias_out)
{
    const int gid = blockIdx.x * 256 + threadIdx.x;
    if (gid < OUT_F / 4) {
        float32x4 b4 = __builtin_nontemporal_load((const float32x4*)bias + gid);
        __builtin_nontemporal_store(b4, (float32x4*)bias_out + gid);
    }

    const int nx4 = TOKENS * IN_F / 4;
    const int nw4 = OUT_F * IN_F / 4;
    for (int i = gid; i < nx4 + nw4; i += gridDim.x * 256) {
        const int* s; uint32_t* d; int j;
        if (i < nx4) { s = x32; d = x8; j = i; }
        else         { s = w32; d = w8; j = i - nx4; }
        int32x4 v = __builtin_nontemporal_load((const int32x4*)s + j);
        d[j] = (uint32_t)(v[0] & 0xff) | ((uint32_t)(v[1] & 0xff) << 8) |
               ((uint32_t)(v[2] & 0xff) << 16) | ((uint32_t)v[3] << 24);
    }
}

// ---- 256x256 i8 GEMM: m201-style fine-grained 4-phase schedule ------------
// 8 waves 2M x 4N: each wave reads ONE A-half (its 128 rows) + ONE B-half.
// Phase q: {ds_read next chunk (4 or 12) | stage 2 halves | BAR | lgkm(cnt of
// just-issued) | sched_barrier | 16 MFMA chunk q | BAR}. Reads run one phase
// ahead -> lgkm never waits on this phase's reads. vmcnt(4) once per tile at
// ph2 (before its opening barrier -> cross-wave visible for ph3's reads).
__global__ __launch_bounds__(512, 2)
void w8a8_gemm_kernel(const int8_t* __restrict__ x,
                      const int8_t* __restrict__ w,
                      const float* __restrict__ scale,
                      const float* __restrict__ bias,
                      float* __restrict__ out)
{
    __shared__ int8_t smem[131072];            // staging: lA | lB ; epilogue reuse
    int8_t* lA = smem;                         // [buf][half][128][128B] 64 KB
    int8_t* lB = smem + 65536;                 // 64 KB

    const int tid = threadIdx.x;
    const int wv  = tid >> 6;
    const int l   = tid & 63;
    const int mgrp = wv >> 2;              // 0..1  A-half (128-row strip)
    const int ncol = wv & 3;               // 0..3  64-col strip
    const int bhalf = ncol >> 1;           // B-half this wave reads
    const int brow  = (ncol & 1) * 64;     // row base within B-half

    // XCD-chunked bijective swizzle (r10-proven): 512 blocks = 8 XCDs x (8bn x 8bm)
    const int xc  = blockIdx.x & 7;
    const int idx = blockIdx.x >> 3;
    const int bn  = (xc & 1) * 8 + (idx & 7);    // 0..15
    const int bm  = (xc >> 1) * 8 + (idx >> 3);  // 0..31

    const int8_t* baseA = x + (size_t)bm * BM * IN_F;
    const int8_t* baseB = w + (size_t)bn * BN * IN_F;

    // staging: T2 swizzle via pre-swizzled global source (rule 21)
    const int seg0 = wv * 2, seg1 = wv * 2 + 1;   // 16 segs x 8 rows per half
    const int r8   = l >> 3;
    const int swc  = (((l & 7) ^ r8) << 4);

    const int8_t* pA0 = baseA + (size_t)(seg0 * 8 + r8) * IN_F + swc;
    const int8_t* pA1 = baseA + (size_t)(seg1 * 8 + r8) * IN_F + swc;
    const int8_t* pB0 = baseB + (size_t)(seg0 * 8 + r8) * IN_F + swc;
    const int8_t* pB1 = baseB + (size_t)(seg1 * 8 + r8) * IN_F + swc;

    // fragment read addressing
    const int fr  = l & 15;
    const int xk  = (l & 7) << 4;
    const int cb0 = (l >> 4) << 4;

    int32x4 acc[4][2][4];                  // [chunk][mi][ni]
#pragma unroll
    for (int q = 0; q < 4; ++q)
#pragma unroll
        for (int mi = 0; mi < 2; ++mi)
#pragma unroll
            for (int ni = 0; ni < 4; ++ni)
                acc[q][mi][ni] = (int32x4){0, 0, 0, 0};

    int32x4 aE[2][2], aO[2][2];            // A-chunk sets (even/odd phase)
    int32x4 bS0[4][2], bS1[4][2];          // B sets (tile parity)

    auto stage_half = [&](int h4) {
        const int kt_ = h4 >> 2;
        const int wh_ = h4 & 3;            // 0:A0 1:A1 2:B0 3:B1
        const size_t off = (size_t)(wh_ & 1) * (128 * IN_F) + (size_t)kt_ * BK;
        const int8_t* s0 = ((wh_ < 2) ? pA0 : pB0) + off;
        const int8_t* s1 = ((wh_ < 2) ? pA1 : pB1) + off;
        int8_t* db = ((wh_ < 2) ? lA : lB) + ((kt_ & 1) << 15) + ((wh_ & 1) << 14);
        __builtin_amdgcn_global_load_lds(
            (const AS1 void*)s0, (AS3 void*)(db + seg0 * 1024), 16, 0, 0);
        __builtin_amdgcn_global_load_lds(
            (const AS1 void*)s1, (AS3 void*)(db + seg1 * 1024), 16, 0, 0);
    };

#define LDCH(DST, TT, Q)                                                               \
    do {                                                                               \
        const int8_t* _p = lA + (((TT) & 1) << 15) + (mgrp << 14);                     \
        _Pragma("unroll") for (int mi = 0; mi < 2; ++mi)                               \
        _Pragma("unroll") for (int ks = 0; ks < 2; ++ks)                               \
            DST[mi][ks] = *(const int32x4*)&_p[((Q) * 32 + mi * 16 + fr) * 128 +       \
                                               (((ks * 64) + cb0) ^ xk)];              \
    } while (0)

#define LDBO(DST, TT)                                                                  \
    do {                                                                               \
        const int8_t* _p = lB + (((TT) & 1) << 15) + (bhalf << 14);                    \
        _Pragma("unroll") for (int ni = 0; ni < 4; ++ni)                               \
        _Pragma("unroll") for (int ks = 0; ks < 2; ++ks)                               \
            DST[ni][ks] = *(const int32x4*)&_p[(brow + ni * 16 + fr) * 128 +           \
                                               (((ks * 64) + cb0) ^ xk)];              \
    } while (0)

#define MMACH(Q, ASET, BSET)                                                           \
    do {                                                                               \
        _Pragma("unroll") for (int mi = 0; mi < 2; ++mi)                               \
        _Pragma("unroll") for (int ni = 0; ni < 4; ++ni)                               \
        _Pragma("unroll") for (int ks = 0; ks < 2; ++ks)                               \
            acc[Q][mi][ni] = __builtin_amdgcn_mfma_i32_16x16x64_i8(                    \
                ASET[mi][ks], BSET[ni][ks], acc[Q][mi][ni], 0, 0, 0);                  \
    } while (0)

#define PH_TAIL(Q, ASET, BCUR)                                                         \
        __builtin_amdgcn_sched_barrier(0);                                             \
        __builtin_amdgcn_s_setprio(1);                                                 \
        MMACH(Q, ASET, BCUR);                                                          \
        __builtin_amdgcn_s_setprio(0);                                                 \
        __builtin_amdgcn_s_barrier()

#define TILE(T, BCUR, BNXT)                                                            \
    do {                                                                               \
        /* ph0: MFMA chunk0 (read last ph3); read chunk1; stage A(t+1) */              \
        LDCH(aO, T, 1);                                                                \
        if ((T) + 1 < NT) { stage_half(4 * ((T) + 1) + 0);                             \
                            stage_half(4 * ((T) + 1) + 1); }                           \
        __builtin_amdgcn_s_barrier();                                                  \
        asm volatile("s_waitcnt lgkmcnt(4)" ::: "memory");                             \
        PH_TAIL(0, aE, BCUR);                                                          \
        /* ph1: MFMA chunk1; read chunk2 */                                            \
        LDCH(aE, T, 2);                                                                \
        __builtin_amdgcn_s_barrier();                                                  \
        asm volatile("s_waitcnt lgkmcnt(4)" ::: "memory");                             \
        PH_TAIL(1, aO, BCUR);                                                          \
        /* ph2: MFMA chunk2; read chunk3; stage B(t+2); vmcnt before BAR */            \
        LDCH(aO, T, 3);                                                                \
        if ((T) + 2 < NT) { stage_half(4 * ((T) + 2) + 2);                             \
                            stage_half(4 * ((T) + 2) + 3);                             \
                            asm volatile("s_waitcnt vmcnt(4)" ::: "memory"); }         \
        else if ((T) + 1 < NT) asm volatile("s_waitcnt vmcnt(0)" ::: "memory");        \
        __builtin_amdgcn_s_barrier();                                                  \
        asm volatile("s_waitcnt lgkmcnt(4)" ::: "memory");                             \
        PH_TAIL(2, aE, BCUR);                                                          \
        /* ph3: MFMA chunk3; read B(t+1)+chunk0(t+1) from other buffer */              \
        if ((T) + 1 < NT) { LDBO(BNXT, (T) + 1); LDCH(aE, (T) + 1, 0); }               \
        __builtin_amdgcn_s_barrier();                                                  \
        if ((T) + 1 < NT) asm volatile("s_waitcnt lgkmcnt(12)" ::: "memory");          \
        else              asm volatile("s_waitcnt lgkmcnt(0)" ::: "memory");           \
        PH_TAIL(3, aO, BCUR);                                                          \
    } while (0)

    // ---- prologue: A(0),B(0) -> buf0; B(1) -> buf1; first 12 reads ----
    stage_half(0); stage_half(1); stage_half(2); stage_half(3);
    stage_half(4 * 1 + 2); stage_half(4 * 1 + 3);
    asm volatile("s_waitcnt vmcnt(4)" ::: "memory");   // A(0),B(0) landed; B(1) flies
    __builtin_amdgcn_s_barrier();
    LDBO(bS0, 0); LDCH(aE, 0, 0);                      // drained by t0-ph0's lgkm(4)

    // ---- main loop: 2 tiles per iteration (static B-set toggle) ----
    for (int t = 0; t < NT; t += 2) {
        TILE(t,     bS0, bS1);
        TILE(t + 1, bS1, bS0);
    }

    // ---- epilogue: LDS-staged, fully coalesced float4 nt stores ----
    __syncthreads();
    int* eL = (int*)smem;
    const int c4   = tid & 63;          // float4 col index within 256-col block
    const int rowt = tid >> 6;          // 0..7
    const float32x4 sc4 = ((const float32x4*)scale)[bn * 64 + c4];
    const float32x4 bf4 = ((const float32x4*)bias )[bn * 64 + c4];
    const __half bh[4] = { __float2half(bf4[0]), __float2half(bf4[1]),
                           __float2half(bf4[2]), __float2half(bf4[3]) };
    const int r0 = (l >> 4) << 2;

    for (int c = 0; c < 4; ++c) {
        if (mgrp == (c >> 1)) {
            const int Qb = (c & 1) * 2;
#pragma unroll
            for (int qq = 0; qq < 2; ++qq)
#pragma unroll
                for (int mi = 0; mi < 2; ++mi)
#pragma unroll
                    for (int ni = 0; ni < 4; ++ni)
#pragma unroll
                        for (int r = 0; r < 4; ++r)
                            eL[(qq * 32 + mi * 16 + r0 + r) * ESTR +
                               ncol * 64 + ni * 16 + fr] = acc[Qb + qq][mi][ni][r];
        }
        __syncthreads();
#pragma unroll
        for (int p = 0; p < 8; ++p) {
            const int rl = p * 8 + rowt;
            int32x4 v = *(const int32x4*)&eL[rl * ESTR + c4 * 4];
            float32x4 o;
#pragma unroll
            for (int j = 0; j < 4; ++j) {
                __half h = __float2half((float)v[j] * sc4[j]);
                o[j] = __half2float(__hadd(h, bh[j]));
            }
            const size_t rowg = (size_t)(bm * 256 + c * 64 + rl);
            __builtin_nontemporal_store(o, (float32x4*)out + rowg * (OUT_F / 4) + bn * 64 + c4);
        }
        __syncthreads();   // copy-out done before next chunk overwrites
    }
#undef LDCH
#undef LDBO
#undef MMACH
#undef PH_TAIL
#undef TILE
}

extern "C" void kernel_launch(void* const* d_in, const int* in_sizes, int n_in,
                              void* d_out, int out_size, void* d_ws, size_t ws_size,
                              hipStream_t stream)
{
    const int*   x32   = (const int*)d_in[0];
    const int*   w32   = (const int*)d_in[1];
    const float* scale = (const float*)d_in[2];
    const float* bias  = (const float*)d_in[3];
    float* out = (float*)d_out;

    int8_t* x8 = (int8_t*)d_ws;
    int8_t* w8 = x8 + (size_t)TOKENS * IN_F;

    pack_all_kernel<<<3072, 256, 0, stream>>>(x32, w32, bias, (uint32_t*)x8, (uint32_t*)w8,
                                              out + (size_t)TOKENS * OUT_F);

    w8a8_gemm_kernel<<<512, 512, 0, stream>>>(x8, w8, scale, bias, out);
}

// Round 15
// 197.794 us; speedup vs baseline: 1.2961x; 1.2961x over previous
//
#include <hip/hip_runtime.h>
#include <hip/hip_fp16.h>
#include <stdint.h>

typedef __attribute__((ext_vector_type(4))) int int32x4;
typedef __attribute__((ext_vector_type(4))) float float32x4;

#define TOKENS 8192
#define IN_F   4096
#define OUT_F  4096
#define BM 128
#define BN 128
#define BK 128              // int8 per K-tile = 128 B rows (proven swizzle geometry)
#define NT (IN_F / BK)      // 32 K-tiles
#define ESTR 132            // epilogue LDS row stride (f32), 128 cols: 2-way alias = free

#define AS1 __attribute__((address_space(1)))
#define AS3 __attribute__((address_space(3)))

// ------- fused pack: int32->int8 for x and w, plus bias tuple-output -------
__global__ __launch_bounds__(256)
void pack_all_kernel(const int* __restrict__ x32, const int* __restrict__ w32,
                     const float* __restrict__ bias,
                     uint32_t* __restrict__ x8, uint32_t* __restrict__ w8,
                     float* __restrict__ bias_out)
{
    const int gid = blockIdx.x * 256 + threadIdx.x;
    if (gid < OUT_F / 4) {
        float32x4 b4 = __builtin_nontemporal_load((const float32x4*)bias + gid);
        __builtin_nontemporal_store(b4, (float32x4*)bias_out + gid);
    }

    const int nx4 = TOKENS * IN_F / 4;
    const int nw4 = OUT_F * IN_F / 4;
    for (int i = gid; i < nx4 + nw4; i += gridDim.x * 256) {
        const int* s; uint32_t* d; int j;
        if (i < nx4) { s = x32; d = x8; j = i; }
        else         { s = w32; d = w8; j = i - nx4; }
        int32x4 v = __builtin_nontemporal_load((const int32x4*)s + j);
        d[j] = (uint32_t)(v[0] & 0xff) | ((uint32_t)(v[1] & 0xff) << 8) |
               ((uint32_t)(v[2] & 0xff) << 16) | ((uint32_t)v[3] << 24);
    }
}

// ---- 128x128 i8 GEMM: 64 KiB LDS -> 2 independent blocks per CU -----------
// 256 threads = 4 waves (2M x 2N), wave-tile 64x64: 16 ds_read_b128 + 32
// MFMA (16x16x64) per K-tile. r12-proven schedule: reads -> stage t+1 ->
// MFMA -> vmcnt(0) -> ONE barrier. Cross-pipe overlap comes from the OTHER
// resident block (m114 mechanism), not intra-block scheduling.
__global__ __launch_bounds__(256, 2)
void w8a8_gemm_kernel(const int8_t* __restrict__ x,
                      const int8_t* __restrict__ w,
                      const float* __restrict__ scale,
                      const float* __restrict__ bias,
                      float* __restrict__ out)
{
    __shared__ int8_t smem[65536];             // lA dbuf 32K | lB dbuf 32K ; epilogue reuse
    int8_t* lA = smem;                         // [2][128][128]
    int8_t* lB = smem + 32768;                 // [2][128][128]

    const int tid = threadIdx.x;
    const int wv  = tid >> 6;              // 0..3
    const int l   = tid & 63;
    const int wm  = wv >> 1;               // 0..1  (64-row strip)
    const int wn  = wv & 1;                // 0..1  (64-col strip)

    // XCD-chunked bijective swizzle: 2048 blocks = 8 XCDs x (16bn x 16bm)
    const int xc  = blockIdx.x & 7;
    const int idx = blockIdx.x >> 3;           // 0..255
    const int bn  = (xc & 1) * 16 + (idx & 15);    // 0..31
    const int bm  = (xc >> 1) * 16 + (idx >> 4);   // 0..63

    const int8_t* baseA = x + (size_t)bm * BM * IN_F;
    const int8_t* baseB = w + (size_t)bn * BN * IN_F;

    // staging: T2 swizzle via pre-swizzled global source (rule 21).
    // One issue = 256 thr x 16 B = 4 KB = 32 rows; 4 issues per 16 KB half.
    const int r8  = l >> 3;
    const int swc = (((l & 7) ^ r8) << 4);
    const int8_t* pA = baseA + (size_t)(wv * 8 + r8) * IN_F + swc;
    const int8_t* pB = baseB + (size_t)(wv * 8 + r8) * IN_F + swc;
    const int dofs = tid << 4;

    // fragment read addressing (proven)
    const int fr  = l & 15;
    const int xk  = (l & 7) << 4;
    const int cb0 = (l >> 4) << 4;

    int32x4 acc[4][4];
#pragma unroll
    for (int mi = 0; mi < 4; ++mi)
#pragma unroll
        for (int ni = 0; ni < 4; ++ni)
            acc[mi][ni] = (int32x4){0, 0, 0, 0};

    int32x4 aF[4][2], bF[4][2];

    auto stage_tile = [&](int t) {
        int8_t* dA = lA + ((t & 1) << 14);
        int8_t* dB = lB + ((t & 1) << 14);
        const size_t co = (size_t)t * BK;
#pragma unroll
        for (int i = 0; i < 4; ++i) {
            __builtin_amdgcn_global_load_lds(
                (const AS1 void*)(pA + (size_t)(i * 32) * IN_F + co),
                (AS3 void*)(dA + i * 4096 + dofs), 16, 0, 0);
            __builtin_amdgcn_global_load_lds(
                (const AS1 void*)(pB + (size_t)(i * 32) * IN_F + co),
                (AS3 void*)(dB + i * 4096 + dofs), 16, 0, 0);
        }
    };

    // ---- prologue: tile 0 ----
    stage_tile(0);
    asm volatile("s_waitcnt vmcnt(0)" ::: "memory");
    __builtin_amdgcn_s_barrier();

    // ---- main loop ----
    for (int t = 0; t < NT; ++t) {
        const int8_t* lAb = lA + ((t & 1) << 14);
        const int8_t* lBb = lB + ((t & 1) << 14);

        // 16 ds_read_b128 (compiler emits counted lgkmcnt under the MFMA burst)
#pragma unroll
        for (int mi = 0; mi < 4; ++mi)
#pragma unroll
            for (int ks = 0; ks < 2; ++ks)
                aF[mi][ks] = *(const int32x4*)&lAb[(wm * 64 + mi * 16 + fr) * 128 +
                                                   (((ks * 64) + cb0) ^ xk)];
#pragma unroll
        for (int ni = 0; ni < 4; ++ni)
#pragma unroll
            for (int ks = 0; ks < 2; ++ks)
                bF[ni][ks] = *(const int32x4*)&lBb[(wn * 64 + ni * 16 + fr) * 128 +
                                                   (((ks * 64) + cb0) ^ xk)];

        if (t + 1 < NT) stage_tile(t + 1);     // -> other buffer, in flight under MFMA

        __builtin_amdgcn_s_setprio(1);
#pragma unroll
        for (int mi = 0; mi < 4; ++mi)
#pragma unroll
            for (int ni = 0; ni < 4; ++ni)
#pragma unroll
                for (int ks = 0; ks < 2; ++ks)
                    acc[mi][ni] = __builtin_amdgcn_mfma_i32_16x16x64_i8(
                        aF[mi][ks], bF[ni][ks], acc[mi][ni], 0, 0, 0);
        __builtin_amdgcn_s_setprio(0);

        if (t + 1 < NT) asm volatile("s_waitcnt vmcnt(0)" ::: "memory");
        __builtin_amdgcn_s_barrier();
    }

    // ---- epilogue: LDS-staged, fully coalesced float4 nt stores ----
    __syncthreads();
    int* eL = (int*)smem;
    const int c4   = tid & 31;          // float4 col index within 128-col block
    const int rowt = tid >> 5;          // 0..7
    const float32x4 sc4 = ((const float32x4*)scale)[bn * 32 + c4];
    const float32x4 bf4 = ((const float32x4*)bias )[bn * 32 + c4];
    const __half bh[4] = { __float2half(bf4[0]), __float2half(bf4[1]),
                           __float2half(bf4[2]), __float2half(bf4[3]) };
    const int r0 = (l >> 4) << 2;

    for (int c = 0; c < 4; ++c) {              // 4 chunks of 32 output rows
        if (wm == (c >> 1)) {
#pragma unroll
            for (int mi2 = 0; mi2 < 2; ++mi2) {
                const int mi = (c & 1) * 2 + mi2;
#pragma unroll
                for (int ni = 0; ni < 4; ++ni)
#pragma unroll
                    for (int r = 0; r < 4; ++r)
                        eL[(mi2 * 16 + r0 + r) * ESTR +
                           wn * 64 + ni * 16 + fr] = acc[mi][ni][r];
            }
        }
        __syncthreads();
#pragma unroll
        for (int p = 0; p < 4; ++p) {          // 32 rows, 8 per pass
            const int rl = p * 8 + rowt;
            int32x4 v = *(const int32x4*)&eL[rl * ESTR + c4 * 4];
            float32x4 o;
#pragma unroll
            for (int j = 0; j < 4; ++j) {
                __half h = __float2half((float)v[j] * sc4[j]);
                o[j] = __half2float(__hadd(h, bh[j]));
            }
            const size_t rowg = (size_t)(bm * 128 + c * 32 + rl);
            __builtin_nontemporal_store(o, (float32x4*)out + rowg * (OUT_F / 4) + bn * 32 + c4);
        }
        __syncthreads();   // copy-out done before next chunk overwrites
    }
}

extern "C" void kernel_launch(void* const* d_in, const int* in_sizes, int n_in,
                              void* d_out, int out_size, void* d_ws, size_t ws_size,
                              hipStream_t stream)
{
    const int*   x32   = (const int*)d_in[0];
    const int*   w32   = (const int*)d_in[1];
    const float* scale = (const float*)d_in[2];
    const float* bias  = (const float*)d_in[3];
    float* out = (float*)d_out;

    int8_t* x8 = (int8_t*)d_ws;
    int8_t* w8 = x8 + (size_t)TOKENS * IN_F;

    pack_all_kernel<<<3072, 256, 0, stream>>>(x32, w32, bias, (uint32_t*)x8, (uint32_t*)w8,
                                              out + (size_t)TOKENS * OUT_F);

    w8a8_gemm_kernel<<<2048, 256, 0, stream>>>(x8, w8, scale, bias, out);
}